// Round 1
// baseline (814.094 us; speedup 1.0000x reference)
//
#include <hip/hip_runtime.h>

#define D_MODEL 1024
#define NUM_EXPERTS 8
#define CAPACITY 1024
#define D_FF 4096
#define T_TOKENS 8192

typedef unsigned short u16;
typedef __attribute__((ext_vector_type(8))) short short8;
typedef __attribute__((ext_vector_type(4))) float floatx4;

typedef __attribute__((address_space(1))) const void* gptr1_t;
typedef __attribute__((address_space(3))) void* lptr3_t;

__device__ __forceinline__ void async_copy16(void* lds, const void* g) {
  // lane i of the wave writes 16B at lds + i*16; gptr is per-lane.
  __builtin_amdgcn_global_load_lds((gptr1_t)g, (lptr3_t)lds, 16, 0, 0);
}

__device__ __forceinline__ u16 f2bf(float f) {
  union { float f; unsigned int u; } v; v.f = f;
  unsigned int r = (v.u + 0x7FFFu + ((v.u >> 16) & 1u)) >> 16;  // RNE
  return (u16)r;
}

// ---------------- router: logits, softmax, argmax, per-expert compaction ----
__global__ void moe_router(const float* __restrict__ x, const float* __restrict__ Wr,
                           int* __restrict__ counts, float* __restrict__ probsum,
                           float* __restrict__ elist_gate, int* __restrict__ elist_tok) {
  __shared__ float lprob[NUM_EXPERTS];
  if (threadIdx.x < NUM_EXPERTS) lprob[threadIdx.x] = 0.f;
  __syncthreads();
  const int wave = threadIdx.x >> 6, lane = threadIdx.x & 63;
  const int t = blockIdx.x * 4 + wave;
  const float* xr = x + (size_t)t * D_MODEL;
  double acc[8] = {0, 0, 0, 0, 0, 0, 0, 0};
  for (int d = lane; d < D_MODEL; d += 64) {
    float xv = xr[d];
    const float4* w = (const float4*)(Wr + d * 8);
    float4 w0 = w[0], w1 = w[1];
    acc[0] += (double)xv * w0.x; acc[1] += (double)xv * w0.y;
    acc[2] += (double)xv * w0.z; acc[3] += (double)xv * w0.w;
    acc[4] += (double)xv * w1.x; acc[5] += (double)xv * w1.y;
    acc[6] += (double)xv * w1.z; acc[7] += (double)xv * w1.w;
  }
#pragma unroll
  for (int e = 0; e < 8; e++) {
#pragma unroll
    for (int o = 32; o > 0; o >>= 1) acc[e] += __shfl_xor(acc[e], o, 64);
  }
  if (lane == 0) {
    float l[8];
#pragma unroll
    for (int e = 0; e < 8; e++) l[e] = (float)acc[e];
    int am = 0; float mx = l[0];
#pragma unroll
    for (int e = 1; e < 8; e++) if (l[e] > mx) { mx = l[e]; am = e; }
    float p[8], s = 0.f;
#pragma unroll
    for (int e = 0; e < 8; e++) { p[e] = expf(l[e] - mx); s += p[e]; }
    float inv = 1.f / s;
#pragma unroll
    for (int e = 0; e < 8; e++) atomicAdd(&lprob[e], p[e] * inv);
    float gate = inv;  // p[am] == 1 -> max softmax prob
    int slot = atomicAdd(&counts[am], 1);
    elist_gate[am * T_TOKENS + slot] = gate;
    elist_tok[am * T_TOKENS + slot] = t;
  }
  __syncthreads();
  if (threadIdx.x < NUM_EXPERTS) atomicAdd(&probsum[threadIdx.x], lprob[threadIdx.x]);
}

// ---------------- capacity selection: rank by counting (matches stable top_k)
__global__ void moe_rank(const int* __restrict__ counts, const float* __restrict__ elist_gate,
                         const int* __restrict__ elist_tok, int* __restrict__ perm,
                         float* __restrict__ gates_sel) {
  const int e = blockIdx.x >> 3, chunk = blockIdx.x & 7;
  const int n = counts[e];
  __shared__ float g[T_TOKENS];  // 32 KB
  for (int i = threadIdx.x; i < n; i += 256) g[i] = elist_gate[e * T_TOKENS + i];
  __syncthreads();
  const int per = (n + 7) >> 3;
  const int lo = chunk * per;
  const int hi = min(n, lo + per);
  for (int i = lo + threadIdx.x; i < hi; i += 256) {
    const float gi = g[i];
    const int ti = elist_tok[e * T_TOKENS + i];
    int r = 0;
    for (int j = 0; j < n; j++) {
      float gj = g[j];
      if (gj > gi) r++;
      else if (gj == gi && elist_tok[e * T_TOKENS + j] < ti) r++;  // rare tie path
    }
    if (r < CAPACITY) {
      perm[e * CAPACITY + r] = ti;
      gates_sel[e * CAPACITY + r] = gi;
    }
  }
}

// ---------------- load-balancing loss ---------------------------------------
__global__ void moe_loss(const int* __restrict__ counts, const float* __restrict__ probsum,
                         float* __restrict__ loss_out) {
  if (threadIdx.x == 0) {
    float l = 0.f;
    for (int e = 0; e < NUM_EXPERTS; e++)
      l += ((float)counts[e] / 8192.f) * (probsum[e] / 8192.f);
    *loss_out = 8.f * l;
  }
}

// ---------------- gather selected tokens to bf16 [E][C][D] ------------------
__global__ void moe_gather(const float* __restrict__ x, const int* __restrict__ perm,
                           u16* __restrict__ Xg) {
  const int slot = blockIdx.x;     // e*CAPACITY + c
  const int t = perm[slot];
  const int i = threadIdx.x;       // 256 threads x float4 = 1024 elems
  unsigned int o0 = 0, o1 = 0;
  if (t >= 0) {
    float4 v = ((const float4*)(x + (size_t)t * D_MODEL))[i];
    o0 = (unsigned int)f2bf(v.x) | ((unsigned int)f2bf(v.y) << 16);
    o1 = (unsigned int)f2bf(v.z) | ((unsigned int)f2bf(v.w) << 16);
  }
  ((uint2*)(Xg + (size_t)slot * D_MODEL))[i] = make_uint2(o0, o1);
}

// ---------------- transpose + fp32->bf16: W[R][C] -> Wt[C][R] ---------------
__global__ void transpose_bf16(const float* __restrict__ W, u16* __restrict__ Wt,
                               int R, int C) {
  __shared__ float tile[32][33];
  const int e = blockIdx.z;
  const float* Wb = W + (size_t)e * R * C;
  u16* Wtb = Wt + (size_t)e * R * C;
  const int c0 = blockIdx.x * 32, r0 = blockIdx.y * 32;
  const int tx = threadIdx.x & 31, ty = threadIdx.x >> 5;
#pragma unroll
  for (int j = 0; j < 4; j++)
    tile[ty + j * 8][tx] = Wb[(size_t)(r0 + ty + j * 8) * C + (c0 + tx)];
  __syncthreads();
#pragma unroll
  for (int j = 0; j < 4; j++)
    Wtb[(size_t)(c0 + ty + j * 8) * R + (r0 + tx)] = f2bf(tile[tx][ty + j * 8]);
}

// ---------------- GEMM1: H = relu(Xg @ W1 + b1), bf16 out -------------------
// m97 structure: 128x128 tile, BK=32, 4 waves, 16x16x32 bf16 MFMA,
// width-16 global_load_lds staging (LDS rows contiguous — no padding allowed).
__global__ __launch_bounds__(256) void moe_gemm1(const u16* __restrict__ Xg,
                                                 const u16* __restrict__ W1t,
                                                 const float* __restrict__ b1,
                                                 u16* __restrict__ H) {
  constexpr int K = D_MODEL;  // 1024
  const int e = blockIdx.z;
  const int n0 = blockIdx.x * 128;  // f
  const int m0 = blockIdx.y * 128;  // c
  const u16* A = Xg + ((size_t)e * CAPACITY + m0) * K;
  const u16* B = W1t + ((size_t)e * D_FF + n0) * K;
  __shared__ u16 As[128 * 32];
  __shared__ u16 Bs[128 * 32];
  const int tid = threadIdx.x, lane = tid & 63, wave = tid >> 6;
  const int wm = (wave >> 1) * 64, wn = (wave & 1) * 64;
  const int srow = lane >> 2, skseg = (lane & 3) * 8;
  const int q0 = wave * 2, q1 = q0 + 1;
  const u16* Ag0 = A + (size_t)(q0 * 16 + srow) * K + skseg;
  const u16* Ag1 = A + (size_t)(q1 * 16 + srow) * K + skseg;
  const u16* Bg0 = B + (size_t)(q0 * 16 + srow) * K + skseg;
  const u16* Bg1 = B + (size_t)(q1 * 16 + srow) * K + skseg;
  floatx4 acc[4][4] = {};
  const int krd = (lane >> 4) * 8;
  for (int k0 = 0; k0 < K; k0 += 32) {
    __syncthreads();
    async_copy16(As + q0 * 512, Ag0 + k0);
    async_copy16(As + q1 * 512, Ag1 + k0);
    async_copy16(Bs + q0 * 512, Bg0 + k0);
    async_copy16(Bs + q1 * 512, Bg1 + k0);
    __syncthreads();
    short8 a[4], b[4];
#pragma unroll
    for (int i = 0; i < 4; i++)
      a[i] = *(const short8*)&As[(wm + i * 16 + (lane & 15)) * 32 + krd];
#pragma unroll
    for (int j = 0; j < 4; j++)
      b[j] = *(const short8*)&Bs[(wn + j * 16 + (lane & 15)) * 32 + krd];
#pragma unroll
    for (int i = 0; i < 4; i++)
#pragma unroll
      for (int j = 0; j < 4; j++)
        acc[i][j] = __builtin_amdgcn_mfma_f32_16x16x32_bf16(a[i], b[j], acc[i][j], 0, 0, 0);
  }
  u16* Hb = H + (size_t)e * CAPACITY * D_FF;
#pragma unroll
  for (int j = 0; j < 4; j++) {
    const int n = n0 + wn + j * 16 + (lane & 15);
    const float bias = b1[e * D_FF + n];
#pragma unroll
    for (int i = 0; i < 4; i++) {
      const int rb = m0 + wm + i * 16 + ((lane >> 4) * 4);  // C/D: col=lane&15, row=quad*4+reg
#pragma unroll
      for (int r = 0; r < 4; r++) {
        float val = acc[i][j][r] + bias;
        val = val > 0.f ? val : 0.f;
        Hb[(size_t)(rb + r) * D_FF + n] = f2bf(val);
      }
    }
  }
}

// ---------------- GEMM2: out[tok] = (H @ W2 + b2) * gate, scatter -----------
__global__ __launch_bounds__(256) void moe_gemm2(const u16* __restrict__ H,
                                                 const u16* __restrict__ W2t,
                                                 const float* __restrict__ b2,
                                                 const float* __restrict__ gates_sel,
                                                 const int* __restrict__ perm,
                                                 float* __restrict__ out) {
  constexpr int K = D_FF;  // 4096
  const int e = blockIdx.z;
  const int n0 = blockIdx.x * 128;  // d_out
  const int m0 = blockIdx.y * 128;  // c
  const u16* A = H + ((size_t)e * CAPACITY + m0) * K;
  const u16* B = W2t + ((size_t)e * D_MODEL + n0) * K;
  __shared__ u16 As[128 * 32];
  __shared__ u16 Bs[128 * 32];
  const int tid = threadIdx.x, lane = tid & 63, wave = tid >> 6;
  const int wm = (wave >> 1) * 64, wn = (wave & 1) * 64;
  const int srow = lane >> 2, skseg = (lane & 3) * 8;
  const int q0 = wave * 2, q1 = q0 + 1;
  const u16* Ag0 = A + (size_t)(q0 * 16 + srow) * K + skseg;
  const u16* Ag1 = A + (size_t)(q1 * 16 + srow) * K + skseg;
  const u16* Bg0 = B + (size_t)(q0 * 16 + srow) * K + skseg;
  const u16* Bg1 = B + (size_t)(q1 * 16 + srow) * K + skseg;
  floatx4 acc[4][4] = {};
  const int krd = (lane >> 4) * 8;
  for (int k0 = 0; k0 < K; k0 += 32) {
    __syncthreads();
    async_copy16(As + q0 * 512, Ag0 + k0);
    async_copy16(As + q1 * 512, Ag1 + k0);
    async_copy16(Bs + q0 * 512, Bg0 + k0);
    async_copy16(Bs + q1 * 512, Bg1 + k0);
    __syncthreads();
    short8 a[4], b[4];
#pragma unroll
    for (int i = 0; i < 4; i++)
      a[i] = *(const short8*)&As[(wm + i * 16 + (lane & 15)) * 32 + krd];
#pragma unroll
    for (int j = 0; j < 4; j++)
      b[j] = *(const short8*)&Bs[(wn + j * 16 + (lane & 15)) * 32 + krd];
#pragma unroll
    for (int i = 0; i < 4; i++)
#pragma unroll
      for (int j = 0; j < 4; j++)
        acc[i][j] = __builtin_amdgcn_mfma_f32_16x16x32_bf16(a[i], b[j], acc[i][j], 0, 0, 0);
  }
  float bias[4];
#pragma unroll
  for (int j = 0; j < 4; j++) bias[j] = b2[e * D_MODEL + n0 + wn + j * 16 + (lane & 15)];
#pragma unroll
  for (int i = 0; i < 4; i++) {
#pragma unroll
    for (int r = 0; r < 4; r++) {
      const int c = m0 + wm + i * 16 + (lane >> 4) * 4 + r;
      const int t = perm[e * CAPACITY + c];
      if (t < 0) continue;  // dropped / empty slot
      const float gv = gates_sel[e * CAPACITY + c];
      float* orow = out + (size_t)t * D_MODEL + n0 + wn;
#pragma unroll
      for (int j = 0; j < 4; j++)
        orow[j * 16 + (lane & 15)] = (acc[i][j][r] + bias[j]) * gv;
    }
  }
}

// ---------------- launch -----------------------------------------------------
extern "C" void kernel_launch(void* const* d_in, const int* in_sizes, int n_in,
                              void* d_out, int out_size, void* d_ws, size_t ws_size,
                              hipStream_t stream) {
  const float* x  = (const float*)d_in[0];  // [4,2048,1024]
  const float* Wr = (const float*)d_in[1];  // [1024,8]
  const float* W1 = (const float*)d_in[2];  // [8,1024,4096]
  const float* b1 = (const float*)d_in[3];  // [8,4096]
  const float* W2 = (const float*)d_in[4];  // [8,4096,1024]
  const float* b2 = (const float*)d_in[5];  // [8,1024]
  float* out = (float*)d_out;               // 8388608 + 1 (loss)

  char* ws = (char*)d_ws;
  u16* W1t = (u16*)ws;            ws += (size_t)8 * 4096 * 1024 * 2;  // [E][F][D] bf16
  u16* W2t = (u16*)ws;            ws += (size_t)8 * 1024 * 4096 * 2;  // [E][D][F] bf16
  u16* Xg  = (u16*)ws;            ws += (size_t)8 * 1024 * 1024 * 2;  // [E][C][D] bf16
  u16* H   = (u16*)ws;            ws += (size_t)8 * 1024 * 4096 * 2;  // [E][C][F] bf16
  float* elist_gate = (float*)ws; ws += (size_t)8 * 8192 * 4;
  int*   elist_tok  = (int*)ws;   ws += (size_t)8 * 8192 * 4;
  int*   perm       = (int*)ws;   ws += (size_t)8 * 1024 * 4;
  float* gates_sel  = (float*)ws; ws += (size_t)8 * 1024 * 4;
  int*   counts     = (int*)ws;   ws += 8 * 4;
  float* probsum    = (float*)ws; ws += 8 * 4;

  hipMemsetAsync(d_out, 0, (size_t)out_size * sizeof(float), stream);
  hipMemsetAsync(counts, 0, 64, stream);                 // counts + probsum
  hipMemsetAsync(perm, 0xFF, 8 * 1024 * 4, stream);      // -1 = empty slot
  hipMemsetAsync(gates_sel, 0, 8 * 1024 * 4, stream);

  transpose_bf16<<<dim3(128, 32, 8), 256, 0, stream>>>(W1, W1t, 1024, 4096);
  transpose_bf16<<<dim3(32, 128, 8), 256, 0, stream>>>(W2, W2t, 4096, 1024);
  moe_router<<<2048, 256, 0, stream>>>(x, Wr, counts, probsum, elist_gate, elist_tok);
  moe_rank<<<64, 256, 0, stream>>>(counts, elist_gate, elist_tok, perm, gates_sel);
  moe_loss<<<1, 64, 0, stream>>>(counts, probsum, out + (size_t)8388608);
  moe_gather<<<8192, 256, 0, stream>>>(x, perm, Xg);
  moe_gemm1<<<dim3(32, 8, 8), 256, 0, stream>>>(Xg, W1t, b1, H);
  moe_gemm2<<<dim3(8, 8, 8), 256, 0, stream>>>(H, W2t, b2, gates_sel, perm, out);
}

// Round 2
// 758.658 us; speedup vs baseline: 1.0731x; 1.0731x over previous
//
#include <hip/hip_runtime.h>

#define D_MODEL 1024
#define NUM_EXPERTS 8
#define CAPACITY 1024
#define D_FF 4096
#define T_TOKENS 8192

typedef unsigned short u16;
typedef __attribute__((ext_vector_type(8))) short short8;
typedef __attribute__((ext_vector_type(4))) float floatx4;

typedef __attribute__((address_space(1))) const void* gptr1_t;
typedef __attribute__((address_space(3))) void* lptr3_t;

__device__ __forceinline__ void async_copy16(void* lds, const void* g) {
  // lane i of the wave writes 16B at lds + i*16; gptr is per-lane.
  __builtin_amdgcn_global_load_lds((gptr1_t)g, (lptr3_t)lds, 16, 0, 0);
}

__device__ __forceinline__ u16 f2bf(float f) {
  union { float f; unsigned int u; } v; v.f = f;
  unsigned int r = (v.u + 0x7FFFu + ((v.u >> 16) & 1u)) >> 16;  // RNE
  return (u16)r;
}

// ---------------- phase A: logits, softmax, argmax — NO global atomics ------
__global__ __launch_bounds__(256) void moe_logits(const float* __restrict__ x,
                                                  const float* __restrict__ Wr,
                                                  float* __restrict__ gate_arr,
                                                  int* __restrict__ exp_arr,
                                                  float* __restrict__ partial) {
  __shared__ float lprob[NUM_EXPERTS];
  if (threadIdx.x < NUM_EXPERTS) lprob[threadIdx.x] = 0.f;
  __syncthreads();
  const int wave = threadIdx.x >> 6, lane = threadIdx.x & 63;
  const int t = blockIdx.x * 4 + wave;
  const float4* xr = (const float4*)(x + (size_t)t * D_MODEL);
  double acc[8] = {0, 0, 0, 0, 0, 0, 0, 0};
#pragma unroll
  for (int it = 0; it < 4; it++) {
    const int d0 = it * 256 + lane * 4;
    float4 xv = xr[d0 >> 2];
    const float4* w = (const float4*)(Wr + (size_t)d0 * 8);
    float xs[4] = {xv.x, xv.y, xv.z, xv.w};
#pragma unroll
    for (int c = 0; c < 4; c++) {
      float4 w0 = w[c * 2], w1 = w[c * 2 + 1];
      acc[0] += (double)xs[c] * w0.x; acc[1] += (double)xs[c] * w0.y;
      acc[2] += (double)xs[c] * w0.z; acc[3] += (double)xs[c] * w0.w;
      acc[4] += (double)xs[c] * w1.x; acc[5] += (double)xs[c] * w1.y;
      acc[6] += (double)xs[c] * w1.z; acc[7] += (double)xs[c] * w1.w;
    }
  }
#pragma unroll
  for (int e = 0; e < 8; e++) {
#pragma unroll
    for (int o = 32; o > 0; o >>= 1) acc[e] += __shfl_xor(acc[e], o, 64);
  }
  if (lane == 0) {
    float l[8];
#pragma unroll
    for (int e = 0; e < 8; e++) l[e] = (float)acc[e];
    int am = 0; float mx = l[0];
#pragma unroll
    for (int e = 1; e < 8; e++) if (l[e] > mx) { mx = l[e]; am = e; }
    float p[8], s = 0.f;
#pragma unroll
    for (int e = 0; e < 8; e++) { p[e] = expf(l[e] - mx); s += p[e]; }
    float inv = 1.f / s;
#pragma unroll
    for (int e = 0; e < 8; e++) atomicAdd(&lprob[e], p[e] * inv);  // LDS, 4 waves only
    gate_arr[t] = inv;  // p[am]*inv == 1*inv -> max softmax prob
    exp_arr[t] = am;
  }
  __syncthreads();
  if (threadIdx.x < NUM_EXPERTS) partial[blockIdx.x * 8 + threadIdx.x] = lprob[threadIdx.x];
}

// ---------------- phase B: per-expert compact lists (LDS-local counter) -----
__global__ __launch_bounds__(256) void moe_build(const float* __restrict__ gate_arr,
                                                 const int* __restrict__ exp_arr,
                                                 int* __restrict__ counts,
                                                 int* __restrict__ list_tok,
                                                 float* __restrict__ list_gate) {
  const int e = blockIdx.x;
  __shared__ int cnt;
  if (threadIdx.x == 0) cnt = 0;
  __syncthreads();
  for (int i = threadIdx.x; i < T_TOKENS; i += 256) {
    if (exp_arr[i] == e) {
      int s = atomicAdd(&cnt, 1);  // LDS atomic, block-local
      list_tok[e * T_TOKENS + s] = i;
      list_gate[e * T_TOKENS + s] = gate_arr[i];
    }
  }
  __syncthreads();
  if (threadIdx.x == 0) counts[e] = cnt;
}

// ---------------- phase C: rank by counting within own expert's list --------
__global__ __launch_bounds__(256) void moe_rank2(const int* __restrict__ counts,
                                                 const int* __restrict__ list_tok,
                                                 const float* __restrict__ list_gate,
                                                 int* __restrict__ perm,
                                                 float* __restrict__ gates_sel) {
  const int e = blockIdx.x;
  const int n = counts[e];
  const int i = blockIdx.y * 256 + threadIdx.x;
  if (i >= n) return;
  const float gi = list_gate[e * T_TOKENS + i];
  const int ti = list_tok[e * T_TOKENS + i];
  int r = 0;
  for (int j = 0; j < n; j++) {
    const float gj = list_gate[e * T_TOKENS + j];  // wave-uniform, L1-resident
    const int tj = list_tok[e * T_TOKENS + j];
    r += (gj > gi) || (gj == gi && tj < ti);
  }
  if (r < CAPACITY) {
    perm[e * CAPACITY + r] = ti;
    gates_sel[e * CAPACITY + r] = gi;
  }
}

// ---------------- load-balancing loss (reduce partials) ---------------------
__global__ __launch_bounds__(256) void moe_loss2(const int* __restrict__ counts,
                                                 const float* __restrict__ partial,
                                                 float* __restrict__ loss_out) {
  __shared__ float ps[NUM_EXPERTS];
  if (threadIdx.x < NUM_EXPERTS) ps[threadIdx.x] = 0.f;
  __syncthreads();
  const int e = threadIdx.x & 7;
  float s = 0.f;
  for (int r = threadIdx.x >> 3; r < 2048; r += 32) s += partial[r * 8 + e];
  atomicAdd(&ps[e], s);
  __syncthreads();
  if (threadIdx.x == 0) {
    float l = 0.f;
    for (int k = 0; k < NUM_EXPERTS; k++)
      l += ((float)counts[k] / 8192.f) * (ps[k] / 8192.f);
    *loss_out = 8.f * l;
  }
}

// ---------------- gather selected tokens to bf16 [E][C][D] ------------------
__global__ void moe_gather(const float* __restrict__ x, const int* __restrict__ perm,
                           u16* __restrict__ Xg) {
  const int slot = blockIdx.x;     // e*CAPACITY + c
  const int t = perm[slot];
  const int i = threadIdx.x;       // 256 threads x float4 = 1024 elems
  unsigned int o0 = 0, o1 = 0;
  if (t >= 0) {
    float4 v = ((const float4*)(x + (size_t)t * D_MODEL))[i];
    o0 = (unsigned int)f2bf(v.x) | ((unsigned int)f2bf(v.y) << 16);
    o1 = (unsigned int)f2bf(v.z) | ((unsigned int)f2bf(v.w) << 16);
  }
  ((uint2*)(Xg + (size_t)slot * D_MODEL))[i] = make_uint2(o0, o1);
}

// ---------------- transpose + fp32->bf16: W[R][C] -> Wt[C][R] ---------------
__global__ void transpose_bf16(const float* __restrict__ W, u16* __restrict__ Wt,
                               int R, int C) {
  __shared__ float tile[32][33];
  const int e = blockIdx.z;
  const float* Wb = W + (size_t)e * R * C;
  u16* Wtb = Wt + (size_t)e * R * C;
  const int c0 = blockIdx.x * 32, r0 = blockIdx.y * 32;
  const int tx = threadIdx.x & 31, ty = threadIdx.x >> 5;
#pragma unroll
  for (int j = 0; j < 4; j++)
    tile[ty + j * 8][tx] = Wb[(size_t)(r0 + ty + j * 8) * C + (c0 + tx)];
  __syncthreads();
#pragma unroll
  for (int j = 0; j < 4; j++)
    Wtb[(size_t)(c0 + ty + j * 8) * R + (r0 + tx)] = f2bf(tile[tx][ty + j * 8]);
}

// ---------------- GEMM1: H = relu(Xg @ W1 + b1), bf16 out -------------------
// m97 structure: 128x128 tile, BK=32, 4 waves, 16x16x32 bf16 MFMA,
// width-16 global_load_lds staging (LDS rows contiguous — no padding allowed).
__global__ __launch_bounds__(256) void moe_gemm1(const u16* __restrict__ Xg,
                                                 const u16* __restrict__ W1t,
                                                 const float* __restrict__ b1,
                                                 u16* __restrict__ H) {
  constexpr int K = D_MODEL;  // 1024
  const int e = blockIdx.z;
  const int n0 = blockIdx.x * 128;  // f
  const int m0 = blockIdx.y * 128;  // c
  const u16* A = Xg + ((size_t)e * CAPACITY + m0) * K;
  const u16* B = W1t + ((size_t)e * D_FF + n0) * K;
  __shared__ u16 As[128 * 32];
  __shared__ u16 Bs[128 * 32];
  const int tid = threadIdx.x, lane = tid & 63, wave = tid >> 6;
  const int wm = (wave >> 1) * 64, wn = (wave & 1) * 64;
  const int srow = lane >> 2, skseg = (lane & 3) * 8;
  const int q0 = wave * 2, q1 = q0 + 1;
  const u16* Ag0 = A + (size_t)(q0 * 16 + srow) * K + skseg;
  const u16* Ag1 = A + (size_t)(q1 * 16 + srow) * K + skseg;
  const u16* Bg0 = B + (size_t)(q0 * 16 + srow) * K + skseg;
  const u16* Bg1 = B + (size_t)(q1 * 16 + srow) * K + skseg;
  floatx4 acc[4][4] = {};
  const int krd = (lane >> 4) * 8;
  for (int k0 = 0; k0 < K; k0 += 32) {
    __syncthreads();
    async_copy16(As + q0 * 512, Ag0 + k0);
    async_copy16(As + q1 * 512, Ag1 + k0);
    async_copy16(Bs + q0 * 512, Bg0 + k0);
    async_copy16(Bs + q1 * 512, Bg1 + k0);
    __syncthreads();
    short8 a[4], b[4];
#pragma unroll
    for (int i = 0; i < 4; i++)
      a[i] = *(const short8*)&As[(wm + i * 16 + (lane & 15)) * 32 + krd];
#pragma unroll
    for (int j = 0; j < 4; j++)
      b[j] = *(const short8*)&Bs[(wn + j * 16 + (lane & 15)) * 32 + krd];
#pragma unroll
    for (int i = 0; i < 4; i++)
#pragma unroll
      for (int j = 0; j < 4; j++)
        acc[i][j] = __builtin_amdgcn_mfma_f32_16x16x32_bf16(a[i], b[j], acc[i][j], 0, 0, 0);
  }
  u16* Hb = H + (size_t)e * CAPACITY * D_FF;
#pragma unroll
  for (int j = 0; j < 4; j++) {
    const int n = n0 + wn + j * 16 + (lane & 15);
    const float bias = b1[e * D_FF + n];
#pragma unroll
    for (int i = 0; i < 4; i++) {
      const int rb = m0 + wm + i * 16 + ((lane >> 4) * 4);  // C/D: col=lane&15, row=quad*4+reg
#pragma unroll
      for (int r = 0; r < 4; r++) {
        float val = acc[i][j][r] + bias;
        val = val > 0.f ? val : 0.f;
        Hb[(size_t)(rb + r) * D_FF + n] = f2bf(val);
      }
    }
  }
}

// ---------------- GEMM2: out[tok] = (H @ W2 + b2) * gate, scatter -----------
__global__ __launch_bounds__(256) void moe_gemm2(const u16* __restrict__ H,
                                                 const u16* __restrict__ W2t,
                                                 const float* __restrict__ b2,
                                                 const float* __restrict__ gates_sel,
                                                 const int* __restrict__ perm,
                                                 float* __restrict__ out) {
  constexpr int K = D_FF;  // 4096
  const int e = blockIdx.z;
  const int n0 = blockIdx.x * 128;  // d_out
  const int m0 = blockIdx.y * 128;  // c
  const u16* A = H + ((size_t)e * CAPACITY + m0) * K;
  const u16* B = W2t + ((size_t)e * D_MODEL + n0) * K;
  __shared__ u16 As[128 * 32];
  __shared__ u16 Bs[128 * 32];
  const int tid = threadIdx.x, lane = tid & 63, wave = tid >> 6;
  const int wm = (wave >> 1) * 64, wn = (wave & 1) * 64;
  const int srow = lane >> 2, skseg = (lane & 3) * 8;
  const int q0 = wave * 2, q1 = q0 + 1;
  const u16* Ag0 = A + (size_t)(q0 * 16 + srow) * K + skseg;
  const u16* Ag1 = A + (size_t)(q1 * 16 + srow) * K + skseg;
  const u16* Bg0 = B + (size_t)(q0 * 16 + srow) * K + skseg;
  const u16* Bg1 = B + (size_t)(q1 * 16 + srow) * K + skseg;
  floatx4 acc[4][4] = {};
  const int krd = (lane >> 4) * 8;
  for (int k0 = 0; k0 < K; k0 += 32) {
    __syncthreads();
    async_copy16(As + q0 * 512, Ag0 + k0);
    async_copy16(As + q1 * 512, Ag1 + k0);
    async_copy16(Bs + q0 * 512, Bg0 + k0);
    async_copy16(Bs + q1 * 512, Bg1 + k0);
    __syncthreads();
    short8 a[4], b[4];
#pragma unroll
    for (int i = 0; i < 4; i++)
      a[i] = *(const short8*)&As[(wm + i * 16 + (lane & 15)) * 32 + krd];
#pragma unroll
    for (int j = 0; j < 4; j++)
      b[j] = *(const short8*)&Bs[(wn + j * 16 + (lane & 15)) * 32 + krd];
#pragma unroll
    for (int i = 0; i < 4; i++)
#pragma unroll
      for (int j = 0; j < 4; j++)
        acc[i][j] = __builtin_amdgcn_mfma_f32_16x16x32_bf16(a[i], b[j], acc[i][j], 0, 0, 0);
  }
  float bias[4];
#pragma unroll
  for (int j = 0; j < 4; j++) bias[j] = b2[e * D_MODEL + n0 + wn + j * 16 + (lane & 15)];
#pragma unroll
  for (int i = 0; i < 4; i++) {
#pragma unroll
    for (int r = 0; r < 4; r++) {
      const int c = m0 + wm + i * 16 + (lane >> 4) * 4 + r;
      const int t = perm[e * CAPACITY + c];
      if (t < 0) continue;  // dropped / empty slot
      const float gv = gates_sel[e * CAPACITY + c];
      float* orow = out + (size_t)t * D_MODEL + n0 + wn;
#pragma unroll
      for (int j = 0; j < 4; j++)
        orow[j * 16 + (lane & 15)] = (acc[i][j][r] + bias[j]) * gv;
    }
  }
}

// ---------------- launch -----------------------------------------------------
extern "C" void kernel_launch(void* const* d_in, const int* in_sizes, int n_in,
                              void* d_out, int out_size, void* d_ws, size_t ws_size,
                              hipStream_t stream) {
  const float* x  = (const float*)d_in[0];  // [4,2048,1024]
  const float* Wr = (const float*)d_in[1];  // [1024,8]
  const float* W1 = (const float*)d_in[2];  // [8,1024,4096]
  const float* b1 = (const float*)d_in[3];  // [8,4096]
  const float* W2 = (const float*)d_in[4];  // [8,4096,1024]
  const float* b2 = (const float*)d_in[5];  // [8,1024]
  float* out = (float*)d_out;               // 8388608 + 1 (loss)

  char* ws = (char*)d_ws;
  u16* W1t = (u16*)ws;            ws += (size_t)8 * 4096 * 1024 * 2;  // [E][F][D] bf16
  u16* W2t = (u16*)ws;            ws += (size_t)8 * 1024 * 4096 * 2;  // [E][D][F] bf16
  u16* Xg  = (u16*)ws;            ws += (size_t)8 * 1024 * 1024 * 2;  // [E][C][D] bf16
  u16* H   = (u16*)ws;            ws += (size_t)8 * 1024 * 4096 * 2;  // [E][C][F] bf16
  float* gate_arr  = (float*)ws;  ws += (size_t)T_TOKENS * 4;
  int*   exp_arr   = (int*)ws;    ws += (size_t)T_TOKENS * 4;
  float* partial   = (float*)ws;  ws += (size_t)2048 * 8 * 4;
  int*   list_tok  = (int*)ws;    ws += (size_t)8 * T_TOKENS * 4;
  float* list_gate = (float*)ws;  ws += (size_t)8 * T_TOKENS * 4;
  int*   perm      = (int*)ws;    ws += (size_t)8 * 1024 * 4;
  float* gates_sel = (float*)ws;  ws += (size_t)8 * 1024 * 4;
  int*   counts    = (int*)ws;    ws += 8 * 4;

  hipMemsetAsync(d_out, 0, (size_t)out_size * sizeof(float), stream);
  hipMemsetAsync(perm, 0xFF, 8 * 1024 * 4, stream);      // -1 = empty slot
  hipMemsetAsync(gates_sel, 0, 8 * 1024 * 4, stream);

  transpose_bf16<<<dim3(128, 32, 8), 256, 0, stream>>>(W1, W1t, 1024, 4096);
  transpose_bf16<<<dim3(32, 128, 8), 256, 0, stream>>>(W2, W2t, 4096, 1024);
  moe_logits<<<2048, 256, 0, stream>>>(x, Wr, gate_arr, exp_arr, partial);
  moe_build<<<8, 256, 0, stream>>>(gate_arr, exp_arr, counts, list_tok, list_gate);
  moe_rank2<<<dim3(8, 32), 256, 0, stream>>>(counts, list_tok, list_gate, perm, gates_sel);
  moe_loss2<<<1, 256, 0, stream>>>(counts, partial, out + (size_t)8388608);
  moe_gather<<<8192, 256, 0, stream>>>(x, perm, Xg);
  moe_gemm1<<<dim3(32, 8, 8), 256, 0, stream>>>(Xg, W1t, b1, H);
  moe_gemm2<<<dim3(8, 8, 8), 256, 0, stream>>>(H, W2t, b2, gates_sel, perm, out);
}

// Round 3
// 688.566 us; speedup vs baseline: 1.1823x; 1.1018x over previous
//
#include <hip/hip_runtime.h>

#define D_MODEL 1024
#define NUM_EXPERTS 8
#define CAPACITY 1024
#define D_FF 4096
#define T_TOKENS 8192

typedef unsigned short u16;
typedef __attribute__((ext_vector_type(8))) short short8;
typedef __attribute__((ext_vector_type(4))) float floatx4;

typedef __attribute__((address_space(1))) const void* gptr1_t;
typedef __attribute__((address_space(3))) void* lptr3_t;

__device__ __forceinline__ void async_copy16(void* lds, const void* g) {
  // wave-uniform LDS base; lane i writes 16B at lds + i*16; gptr is per-lane.
  __builtin_amdgcn_global_load_lds((gptr1_t)g, (lptr3_t)lds, 16, 0, 0);
}

__device__ __forceinline__ u16 f2bf(float f) {
  union { float f; unsigned int u; } v; v.f = f;
  unsigned int r = (v.u + 0x7FFFu + ((v.u >> 16) & 1u)) >> 16;  // RNE
  return (u16)r;
}

// ---------------- phase A: logits, softmax, argmax — NO global atomics ------
__global__ __launch_bounds__(256) void moe_logits(const float* __restrict__ x,
                                                  const float* __restrict__ Wr,
                                                  float* __restrict__ gate_arr,
                                                  int* __restrict__ exp_arr,
                                                  float* __restrict__ partial) {
  __shared__ float lprob[NUM_EXPERTS];
  if (threadIdx.x < NUM_EXPERTS) lprob[threadIdx.x] = 0.f;
  __syncthreads();
  const int wave = threadIdx.x >> 6, lane = threadIdx.x & 63;
  const int t = blockIdx.x * 4 + wave;
  const float4* xr = (const float4*)(x + (size_t)t * D_MODEL);
  double acc[8] = {0, 0, 0, 0, 0, 0, 0, 0};
#pragma unroll
  for (int it = 0; it < 4; it++) {
    const int d0 = it * 256 + lane * 4;
    float4 xv = xr[d0 >> 2];
    const float4* w = (const float4*)(Wr + (size_t)d0 * 8);
    float xs[4] = {xv.x, xv.y, xv.z, xv.w};
#pragma unroll
    for (int c = 0; c < 4; c++) {
      float4 w0 = w[c * 2], w1 = w[c * 2 + 1];
      acc[0] += (double)xs[c] * w0.x; acc[1] += (double)xs[c] * w0.y;
      acc[2] += (double)xs[c] * w0.z; acc[3] += (double)xs[c] * w0.w;
      acc[4] += (double)xs[c] * w1.x; acc[5] += (double)xs[c] * w1.y;
      acc[6] += (double)xs[c] * w1.z; acc[7] += (double)xs[c] * w1.w;
    }
  }
#pragma unroll
  for (int e = 0; e < 8; e++) {
#pragma unroll
    for (int o = 32; o > 0; o >>= 1) acc[e] += __shfl_xor(acc[e], o, 64);
  }
  if (lane == 0) {
    float l[8];
#pragma unroll
    for (int e = 0; e < 8; e++) l[e] = (float)acc[e];
    int am = 0; float mx = l[0];
#pragma unroll
    for (int e = 1; e < 8; e++) if (l[e] > mx) { mx = l[e]; am = e; }
    float p[8], s = 0.f;
#pragma unroll
    for (int e = 0; e < 8; e++) { p[e] = expf(l[e] - mx); s += p[e]; }
    float inv = 1.f / s;
#pragma unroll
    for (int e = 0; e < 8; e++) atomicAdd(&lprob[e], p[e] * inv);  // LDS, 4 waves only
    gate_arr[t] = inv;  // p[am]*inv == 1*inv -> max softmax prob
    exp_arr[t] = am;
  }
  __syncthreads();
  if (threadIdx.x < NUM_EXPERTS) partial[blockIdx.x * 8 + threadIdx.x] = lprob[threadIdx.x];
}

// ---------------- phase B: per-expert compact lists (LDS-local counter) -----
__global__ __launch_bounds__(256) void moe_build(const float* __restrict__ gate_arr,
                                                 const int* __restrict__ exp_arr,
                                                 int* __restrict__ counts,
                                                 int* __restrict__ list_tok,
                                                 float* __restrict__ list_gate) {
  const int e = blockIdx.x;
  __shared__ int cnt;
  if (threadIdx.x == 0) cnt = 0;
  __syncthreads();
  for (int i = threadIdx.x; i < T_TOKENS; i += 256) {
    if (exp_arr[i] == e) {
      int s = atomicAdd(&cnt, 1);  // LDS atomic, block-local
      list_tok[e * T_TOKENS + s] = i;
      list_gate[e * T_TOKENS + s] = gate_arr[i];
    }
  }
  __syncthreads();
  if (threadIdx.x == 0) counts[e] = cnt;
}

// ---------------- phase C: rank by counting within own expert's list --------
__global__ __launch_bounds__(256) void moe_rank2(const int* __restrict__ counts,
                                                 const int* __restrict__ list_tok,
                                                 const float* __restrict__ list_gate,
                                                 int* __restrict__ perm,
                                                 float* __restrict__ gates_sel) {
  const int e = blockIdx.x;
  const int n = counts[e];
  const int i = blockIdx.y * 256 + threadIdx.x;
  if (i >= n) return;
  const float gi = list_gate[e * T_TOKENS + i];
  const int ti = list_tok[e * T_TOKENS + i];
  int r = 0;
  for (int j = 0; j < n; j++) {
    const float gj = list_gate[e * T_TOKENS + j];  // wave-uniform, L1-resident
    const int tj = list_tok[e * T_TOKENS + j];
    r += (gj > gi) || (gj == gi && tj < ti);
  }
  if (r < CAPACITY) {
    perm[e * CAPACITY + r] = ti;
    gates_sel[e * CAPACITY + r] = gi;
  }
}

// ---------------- load-balancing loss (reduce partials) ---------------------
__global__ __launch_bounds__(256) void moe_loss2(const int* __restrict__ counts,
                                                 const float* __restrict__ partial,
                                                 float* __restrict__ loss_out) {
  __shared__ float ps[NUM_EXPERTS];
  if (threadIdx.x < NUM_EXPERTS) ps[threadIdx.x] = 0.f;
  __syncthreads();
  const int e = threadIdx.x & 7;
  float s = 0.f;
  for (int r = threadIdx.x >> 3; r < 2048; r += 32) s += partial[r * 8 + e];
  atomicAdd(&ps[e], s);
  __syncthreads();
  if (threadIdx.x == 0) {
    float l = 0.f;
    for (int k = 0; k < NUM_EXPERTS; k++)
      l += ((float)counts[k] / 8192.f) * (ps[k] / 8192.f);
    *loss_out = 8.f * l;
  }
}

// ---------------- gather selected tokens to bf16 [E][C][D] ------------------
__global__ void moe_gather(const float* __restrict__ x, const int* __restrict__ perm,
                           u16* __restrict__ Xg) {
  const int slot = blockIdx.x;     // e*CAPACITY + c
  const int t = perm[slot];
  const int i = threadIdx.x;       // 256 threads x float4 = 1024 elems
  unsigned int o0 = 0, o1 = 0;
  if (t >= 0) {
    float4 v = ((const float4*)(x + (size_t)t * D_MODEL))[i];
    o0 = (unsigned int)f2bf(v.x) | ((unsigned int)f2bf(v.y) << 16);
    o1 = (unsigned int)f2bf(v.z) | ((unsigned int)f2bf(v.w) << 16);
  }
  ((uint2*)(Xg + (size_t)slot * D_MODEL))[i] = make_uint2(o0, o1);
}

// ---------------- transpose + fp32->bf16: W[R][C] -> Wt[C][R], 64x64 tiles --
__global__ __launch_bounds__(256) void transpose64(const float* __restrict__ W,
                                                   u16* __restrict__ Wt, int R, int C) {
  __shared__ float tile[64][65];
  const int e = blockIdx.z;
  const float* Wb = W + (size_t)e * R * C;
  u16* Wtb = Wt + (size_t)e * R * C;
  const int c0 = blockIdx.x * 64, r0 = blockIdx.y * 64;
  const int lr = threadIdx.x >> 4;          // 0..15
  const int lc = (threadIdx.x & 15) * 4;    // 0..60
#pragma unroll
  for (int it = 0; it < 4; it++) {
    float4 v = *(const float4*)&Wb[(size_t)(r0 + lr + it * 16) * C + c0 + lc];
    tile[lr + it * 16][lc + 0] = v.x;
    tile[lr + it * 16][lc + 1] = v.y;
    tile[lr + it * 16][lc + 2] = v.z;
    tile[lr + it * 16][lc + 3] = v.w;
  }
  __syncthreads();
  const int cc = threadIdx.x >> 3;          // 0..31
  const int rb = (threadIdx.x & 7) * 8;     // 0..56
#pragma unroll
  for (int it = 0; it < 2; it++) {
    const int c = cc + it * 32;
    uint4 o;
    o.x = (unsigned)f2bf(tile[rb + 0][c]) | ((unsigned)f2bf(tile[rb + 1][c]) << 16);
    o.y = (unsigned)f2bf(tile[rb + 2][c]) | ((unsigned)f2bf(tile[rb + 3][c]) << 16);
    o.z = (unsigned)f2bf(tile[rb + 4][c]) | ((unsigned)f2bf(tile[rb + 5][c]) << 16);
    o.w = (unsigned)f2bf(tile[rb + 6][c]) | ((unsigned)f2bf(tile[rb + 7][c]) << 16);
    *(uint4*)&Wtb[(size_t)(c0 + c) * R + r0 + rb] = o;
  }
}

// ---------------- GEMM1: H = relu(Xg @ W1 + b1), bf16 out -------------------
// 128x128 tile, BK=32, xor-granule LDS swizzle f(r)=(r>>1)&3 (2-way free),
// XCD-locality: blockIdx.x = expert.
__global__ __launch_bounds__(256) void moe_gemm1(const u16* __restrict__ Xg,
                                                 const u16* __restrict__ W1t,
                                                 const float* __restrict__ b1,
                                                 u16* __restrict__ H) {
  constexpr int K = D_MODEL;  // 1024
  const int e = blockIdx.x;
  const int n0 = blockIdx.y * 128;  // f
  const int m0 = blockIdx.z * 128;  // c
  const u16* A = Xg + ((size_t)e * CAPACITY + m0) * K;
  const u16* B = W1t + ((size_t)e * D_FF + n0) * K;
  __shared__ u16 As[128 * 32];
  __shared__ u16 Bs[128 * 32];
  const int tid = threadIdx.x, lane = tid & 63, wave = tid >> 6;
  const int wm = (wave >> 1) * 64, wn = (wave & 1) * 64;
  // staging geometry: call q covers rows [16q,16q+16); lane -> (row q*16+l/4, pos l&3)
  // fetches global kseg s = (l&3) ^ ((l/4 >> 1)&3)   [xor-granule swizzle]
  const int r_l = lane >> 2;                 // 0..15
  const int s4 = (lane & 3) ^ ((r_l >> 1) & 3);
  const int q0 = wave * 2, q1 = q0 + 1;
  const u16* Ag0 = A + (size_t)(q0 * 16 + r_l) * K + s4 * 8;
  const u16* Ag1 = A + (size_t)(q1 * 16 + r_l) * K + s4 * 8;
  const u16* Bg0 = B + (size_t)(q0 * 16 + r_l) * K + s4 * 8;
  const u16* Bg1 = B + (size_t)(q1 * 16 + r_l) * K + s4 * 8;
  floatx4 acc[4][4] = {};
  const int s_log = lane >> 4;               // logical kseg for frag read
  const int pxor = (((lane & 15) >> 1) & 3); // f(row) depends only on lane&15
  const int pgr = (s_log ^ pxor) * 8;        // physical granule offset (elems)
  for (int k0 = 0; k0 < K; k0 += 32) {
    __syncthreads();
    async_copy16(As + q0 * 512, Ag0 + k0);
    async_copy16(As + q1 * 512, Ag1 + k0);
    async_copy16(Bs + q0 * 512, Bg0 + k0);
    async_copy16(Bs + q1 * 512, Bg1 + k0);
    __syncthreads();
    short8 a[4], b[4];
#pragma unroll
    for (int i = 0; i < 4; i++)
      a[i] = *(const short8*)&As[(wm + i * 16 + (lane & 15)) * 32 + pgr];
#pragma unroll
    for (int j = 0; j < 4; j++)
      b[j] = *(const short8*)&Bs[(wn + j * 16 + (lane & 15)) * 32 + pgr];
#pragma unroll
    for (int i = 0; i < 4; i++)
#pragma unroll
      for (int j = 0; j < 4; j++)
        acc[i][j] = __builtin_amdgcn_mfma_f32_16x16x32_bf16(a[i], b[j], acc[i][j], 0, 0, 0);
  }
  u16* Hb = H + (size_t)e * CAPACITY * D_FF;
#pragma unroll
  for (int j = 0; j < 4; j++) {
    const int n = n0 + wn + j * 16 + (lane & 15);
    const float bias = b1[e * D_FF + n];
#pragma unroll
    for (int i = 0; i < 4; i++) {
      const int rb = m0 + wm + i * 16 + ((lane >> 4) * 4);  // C/D: col=lane&15, row=quad*4+reg
#pragma unroll
      for (int r = 0; r < 4; r++) {
        float val = acc[i][j][r] + bias;
        val = val > 0.f ? val : 0.f;
        Hb[(size_t)(rb + r) * D_FF + n] = f2bf(val);
      }
    }
  }
}

// ---------------- GEMM2: out[tok] = (H @ W2 + b2) * gate, scatter -----------
// 128x128 tile, BK=64 (half the barriers), xor-granule swizzle f(r)=r&7
// (conflict-free b128 reads), XCD-locality: blockIdx.x = expert.
__global__ __launch_bounds__(256) void moe_gemm2(const u16* __restrict__ H,
                                                 const u16* __restrict__ W2t,
                                                 const float* __restrict__ b2,
                                                 const float* __restrict__ gates_sel,
                                                 const int* __restrict__ perm,
                                                 float* __restrict__ out) {
  constexpr int K = D_FF;  // 4096
  const int e = blockIdx.x;
  const int n0 = blockIdx.y * 128;  // d_out
  const int m0 = blockIdx.z * 128;  // c
  const u16* A = H + ((size_t)e * CAPACITY + m0) * K;
  const u16* B = W2t + ((size_t)e * D_MODEL + n0) * K;
  __shared__ u16 As[128 * 64];  // 16 KB
  __shared__ u16 Bs[128 * 64];  // 16 KB
  const int tid = threadIdx.x, lane = tid & 63, wave = tid >> 6;
  const int wm = (wave >> 1) * 64, wn = (wave & 1) * 64;
  // staging: wave w covers rows [32w,32w+32) per tile, 4 calls x 8 rows.
  // lane -> (row +l/8, pos l&7), fetches global kseg s = (l&7) ^ (l/8)
  const int r_l = lane >> 3;                 // 0..7
  const int s8 = (lane & 7) ^ r_l;
  const u16* Ap[4]; const u16* Bp[4];
#pragma unroll
  for (int c = 0; c < 4; c++) {
    const int row = 32 * wave + 8 * c + r_l;
    Ap[c] = A + (size_t)row * K + s8 * 8;
    Bp[c] = B + (size_t)row * K + s8 * 8;
  }
  floatx4 acc[4][4] = {};
  const int lxor = lane & 7;                 // f(row) = row&7 = lane&7 for frag rows
  for (int k0 = 0; k0 < K; k0 += 64) {
    __syncthreads();
#pragma unroll
    for (int c = 0; c < 4; c++)
      async_copy16(As + (32 * wave + 8 * c) * 64, Ap[c] + k0);
#pragma unroll
    for (int c = 0; c < 4; c++)
      async_copy16(Bs + (32 * wave + 8 * c) * 64, Bp[c] + k0);
    __syncthreads();
#pragma unroll
    for (int ks = 0; ks < 2; ks++) {
      const int s_log = ks * 4 + (lane >> 4);     // 0..7
      const int pgr = (s_log ^ lxor) * 8;         // physical granule (elems)
      short8 a[4], b[4];
#pragma unroll
      for (int i = 0; i < 4; i++)
        a[i] = *(const short8*)&As[(wm + i * 16 + (lane & 15)) * 64 + pgr];
#pragma unroll
      for (int j = 0; j < 4; j++)
        b[j] = *(const short8*)&Bs[(wn + j * 16 + (lane & 15)) * 64 + pgr];
#pragma unroll
      for (int i = 0; i < 4; i++)
#pragma unroll
        for (int j = 0; j < 4; j++)
          acc[i][j] = __builtin_amdgcn_mfma_f32_16x16x32_bf16(a[i], b[j], acc[i][j], 0, 0, 0);
    }
  }
  float bias[4];
#pragma unroll
  for (int j = 0; j < 4; j++) bias[j] = b2[e * D_MODEL + n0 + wn + j * 16 + (lane & 15)];
#pragma unroll
  for (int i = 0; i < 4; i++) {
#pragma unroll
    for (int r = 0; r < 4; r++) {
      const int c = m0 + wm + i * 16 + (lane >> 4) * 4 + r;
      const int t = perm[e * CAPACITY + c];
      if (t < 0) continue;  // dropped / empty slot
      const float gv = gates_sel[e * CAPACITY + c];
      float* orow = out + (size_t)t * D_MODEL + n0 + wn;
#pragma unroll
      for (int j = 0; j < 4; j++)
        orow[j * 16 + (lane & 15)] = (acc[i][j][r] + bias[j]) * gv;
    }
  }
}

// ---------------- launch -----------------------------------------------------
extern "C" void kernel_launch(void* const* d_in, const int* in_sizes, int n_in,
                              void* d_out, int out_size, void* d_ws, size_t ws_size,
                              hipStream_t stream) {
  const float* x  = (const float*)d_in[0];  // [4,2048,1024]
  const float* Wr = (const float*)d_in[1];  // [1024,8]
  const float* W1 = (const float*)d_in[2];  // [8,1024,4096]
  const float* b1 = (const float*)d_in[3];  // [8,4096]
  const float* W2 = (const float*)d_in[4];  // [8,4096,1024]
  const float* b2 = (const float*)d_in[5];  // [8,1024]
  float* out = (float*)d_out;               // 8388608 + 1 (loss)

  char* ws = (char*)d_ws;
  u16* W1t = (u16*)ws;            ws += (size_t)8 * 4096 * 1024 * 2;  // [E][F][D] bf16
  u16* W2t = (u16*)ws;            ws += (size_t)8 * 1024 * 4096 * 2;  // [E][D][F] bf16
  u16* Xg  = (u16*)ws;            ws += (size_t)8 * 1024 * 1024 * 2;  // [E][C][D] bf16
  u16* H   = (u16*)ws;            ws += (size_t)8 * 1024 * 4096 * 2;  // [E][C][F] bf16
  float* gate_arr  = (float*)ws;  ws += (size_t)T_TOKENS * 4;
  int*   exp_arr   = (int*)ws;    ws += (size_t)T_TOKENS * 4;
  float* partial   = (float*)ws;  ws += (size_t)2048 * 8 * 4;
  int*   list_tok  = (int*)ws;    ws += (size_t)8 * T_TOKENS * 4;
  float* list_gate = (float*)ws;  ws += (size_t)8 * T_TOKENS * 4;
  int*   perm      = (int*)ws;    ws += (size_t)8 * 1024 * 4;
  float* gates_sel = (float*)ws;  ws += (size_t)8 * 1024 * 4;
  int*   counts    = (int*)ws;    ws += 8 * 4;

  hipMemsetAsync(d_out, 0, (size_t)out_size * sizeof(float), stream);
  hipMemsetAsync(perm, 0xFF, 8 * 1024 * 4, stream);      // -1 = empty slot
  hipMemsetAsync(gates_sel, 0, 8 * 1024 * 4, stream);

  transpose64<<<dim3(64, 16, 8), 256, 0, stream>>>(W1, W1t, 1024, 4096);
  transpose64<<<dim3(16, 64, 8), 256, 0, stream>>>(W2, W2t, 4096, 1024);
  moe_logits<<<2048, 256, 0, stream>>>(x, Wr, gate_arr, exp_arr, partial);
  moe_build<<<8, 256, 0, stream>>>(gate_arr, exp_arr, counts, list_tok, list_gate);
  moe_rank2<<<dim3(8, 32), 256, 0, stream>>>(counts, list_tok, list_gate, perm, gates_sel);
  moe_loss2<<<1, 256, 0, stream>>>(counts, partial, out + (size_t)8388608);
  moe_gather<<<8192, 256, 0, stream>>>(x, perm, Xg);
  moe_gemm1<<<dim3(8, 32, 8), 256, 0, stream>>>(Xg, W1t, b1, H);
  moe_gemm2<<<dim3(8, 8, 8), 256, 0, stream>>>(H, W2t, b2, gates_sel, perm, out);
}

// Round 4
// 654.720 us; speedup vs baseline: 1.2434x; 1.0517x over previous
//
#include <hip/hip_runtime.h>

#define D_MODEL 1024
#define NUM_EXPERTS 8
#define CAPACITY 1024
#define D_FF 4096
#define T_TOKENS 8192

typedef unsigned short u16;
typedef __attribute__((ext_vector_type(8))) short short8;
typedef __attribute__((ext_vector_type(4))) float floatx4;

typedef __attribute__((address_space(1))) const void* gptr1_t;
typedef __attribute__((address_space(3))) void* lptr3_t;

__device__ __forceinline__ void async_copy16(void* lds, const void* g) {
  // wave-uniform LDS base; lane i writes 16B at lds + i*16; gptr is per-lane.
  __builtin_amdgcn_global_load_lds((gptr1_t)g, (lptr3_t)lds, 16, 0, 0);
}

__device__ __forceinline__ u16 f2bf(float f) {
  union { float f; unsigned int u; } v; v.f = f;
  unsigned int r = (v.u + 0x7FFFu + ((v.u >> 16) & 1u)) >> 16;  // RNE
  return (u16)r;
}

// ---------------- phase A: logits, softmax, argmax — NO global atomics ------
__global__ __launch_bounds__(256) void moe_logits(const float* __restrict__ x,
                                                  const float* __restrict__ Wr,
                                                  float* __restrict__ gate_arr,
                                                  int* __restrict__ exp_arr,
                                                  float* __restrict__ partial) {
  __shared__ float lprob[NUM_EXPERTS];
  if (threadIdx.x < NUM_EXPERTS) lprob[threadIdx.x] = 0.f;
  __syncthreads();
  const int wave = threadIdx.x >> 6, lane = threadIdx.x & 63;
  const int t = blockIdx.x * 4 + wave;
  const float4* xr = (const float4*)(x + (size_t)t * D_MODEL);
  double acc[8] = {0, 0, 0, 0, 0, 0, 0, 0};
#pragma unroll
  for (int it = 0; it < 4; it++) {
    const int d0 = it * 256 + lane * 4;
    float4 xv = xr[d0 >> 2];
    const float4* w = (const float4*)(Wr + (size_t)d0 * 8);
    float xs[4] = {xv.x, xv.y, xv.z, xv.w};
#pragma unroll
    for (int c = 0; c < 4; c++) {
      float4 w0 = w[c * 2], w1 = w[c * 2 + 1];
      acc[0] += (double)xs[c] * w0.x; acc[1] += (double)xs[c] * w0.y;
      acc[2] += (double)xs[c] * w0.z; acc[3] += (double)xs[c] * w0.w;
      acc[4] += (double)xs[c] * w1.x; acc[5] += (double)xs[c] * w1.y;
      acc[6] += (double)xs[c] * w1.z; acc[7] += (double)xs[c] * w1.w;
    }
  }
#pragma unroll
  for (int e = 0; e < 8; e++) {
#pragma unroll
    for (int o = 32; o > 0; o >>= 1) acc[e] += __shfl_xor(acc[e], o, 64);
  }
  if (lane == 0) {
    float l[8];
#pragma unroll
    for (int e = 0; e < 8; e++) l[e] = (float)acc[e];
    int am = 0; float mx = l[0];
#pragma unroll
    for (int e = 1; e < 8; e++) if (l[e] > mx) { mx = l[e]; am = e; }
    float p[8], s = 0.f;
#pragma unroll
    for (int e = 0; e < 8; e++) { p[e] = expf(l[e] - mx); s += p[e]; }
    float inv = 1.f / s;
#pragma unroll
    for (int e = 0; e < 8; e++) atomicAdd(&lprob[e], p[e] * inv);  // LDS, 4 waves only
    gate_arr[t] = inv;  // p[am]*inv == 1*inv -> max softmax prob
    exp_arr[t] = am;
  }
  __syncthreads();
  if (threadIdx.x < NUM_EXPERTS) partial[blockIdx.x * 8 + threadIdx.x] = lprob[threadIdx.x];
}

// ---------------- phase B: per-expert compact lists (LDS-local counter) -----
__global__ __launch_bounds__(256) void moe_build(const float* __restrict__ gate_arr,
                                                 const int* __restrict__ exp_arr,
                                                 int* __restrict__ counts,
                                                 int* __restrict__ list_tok,
                                                 float* __restrict__ list_gate) {
  const int e = blockIdx.x;
  __shared__ int cnt;
  if (threadIdx.x == 0) cnt = 0;
  __syncthreads();
  for (int i = threadIdx.x; i < T_TOKENS; i += 256) {
    if (exp_arr[i] == e) {
      int s = atomicAdd(&cnt, 1);  // LDS atomic, block-local
      list_tok[e * T_TOKENS + s] = i;
      list_gate[e * T_TOKENS + s] = gate_arr[i];
    }
  }
  __syncthreads();
  if (threadIdx.x == 0) counts[e] = cnt;
}

// ---------------- phase C: rank by counting, list staged in LDS -------------
__global__ __launch_bounds__(256) void moe_rank3(const int* __restrict__ counts,
                                                 const int* __restrict__ list_tok,
                                                 const float* __restrict__ list_gate,
                                                 int* __restrict__ perm,
                                                 float* __restrict__ gates_sel) {
  const int e = blockIdx.x >> 3, chunk = blockIdx.x & 7;
  const int n = counts[e];
  __shared__ float g[T_TOKENS];   // 32 KB
  __shared__ int   tk[T_TOKENS];  // 32 KB
  for (int i = threadIdx.x; i < n; i += 256) {
    g[i] = list_gate[e * T_TOKENS + i];
    tk[i] = list_tok[e * T_TOKENS + i];
  }
  __syncthreads();
  const int per = (n + 7) >> 3;
  const int lo = chunk * per;
  const int hi = min(n, lo + per);
  for (int i = lo + threadIdx.x; i < hi; i += 256) {
    const float gi = g[i];
    const int ti = tk[i];
    int r = 0;
    for (int j = 0; j < n; j++) {
      const float gj = g[j];  // broadcast LDS read — no conflict
      r += (gj > gi) || (gj == gi && tk[j] < ti);
    }
    if (r < CAPACITY) {
      perm[e * CAPACITY + r] = ti;
      gates_sel[e * CAPACITY + r] = gi;
    }
  }
}

// ---------------- load-balancing loss (reduce partials) ---------------------
__global__ __launch_bounds__(256) void moe_loss2(const int* __restrict__ counts,
                                                 const float* __restrict__ partial,
                                                 float* __restrict__ loss_out) {
  __shared__ float ps[NUM_EXPERTS];
  if (threadIdx.x < NUM_EXPERTS) ps[threadIdx.x] = 0.f;
  __syncthreads();
  const int e = threadIdx.x & 7;
  float s = 0.f;
  for (int r = threadIdx.x >> 3; r < 2048; r += 32) s += partial[r * 8 + e];
  atomicAdd(&ps[e], s);
  __syncthreads();
  if (threadIdx.x == 0) {
    float l = 0.f;
    for (int k = 0; k < NUM_EXPERTS; k++)
      l += ((float)counts[k] / 8192.f) * (ps[k] / 8192.f);
    *loss_out = 8.f * l;
  }
}

// ---------------- gather selected tokens to bf16 [E][C][D] ------------------
__global__ void moe_gather(const float* __restrict__ x, const int* __restrict__ perm,
                           u16* __restrict__ Xg) {
  const int slot = blockIdx.x;     // e*CAPACITY + c
  const int t = perm[slot];
  const int i = threadIdx.x;       // 256 threads x float4 = 1024 elems
  unsigned int o0 = 0, o1 = 0;
  if (t >= 0) {
    float4 v = ((const float4*)(x + (size_t)t * D_MODEL))[i];
    o0 = (unsigned int)f2bf(v.x) | ((unsigned int)f2bf(v.y) << 16);
    o1 = (unsigned int)f2bf(v.z) | ((unsigned int)f2bf(v.w) << 16);
  }
  ((uint2*)(Xg + (size_t)slot * D_MODEL))[i] = make_uint2(o0, o1);
}

// ---------------- transpose + fp32->bf16: W[R][C] -> Wt[C][R], 64x64 tiles --
__global__ __launch_bounds__(256) void transpose64(const float* __restrict__ W,
                                                   u16* __restrict__ Wt, int R, int C) {
  __shared__ float tile[64][65];
  const int e = blockIdx.z;
  const float* Wb = W + (size_t)e * R * C;
  u16* Wtb = Wt + (size_t)e * R * C;
  const int c0 = blockIdx.x * 64, r0 = blockIdx.y * 64;
  const int lr = threadIdx.x >> 4;          // 0..15
  const int lc = (threadIdx.x & 15) * 4;    // 0..60
#pragma unroll
  for (int it = 0; it < 4; it++) {
    float4 v = *(const float4*)&Wb[(size_t)(r0 + lr + it * 16) * C + c0 + lc];
    tile[lr + it * 16][lc + 0] = v.x;
    tile[lr + it * 16][lc + 1] = v.y;
    tile[lr + it * 16][lc + 2] = v.z;
    tile[lr + it * 16][lc + 3] = v.w;
  }
  __syncthreads();
  const int cc = threadIdx.x >> 3;          // 0..31
  const int rb = (threadIdx.x & 7) * 8;     // 0..56
#pragma unroll
  for (int it = 0; it < 2; it++) {
    const int c = cc + it * 32;
    uint4 o;
    o.x = (unsigned)f2bf(tile[rb + 0][c]) | ((unsigned)f2bf(tile[rb + 1][c]) << 16);
    o.y = (unsigned)f2bf(tile[rb + 2][c]) | ((unsigned)f2bf(tile[rb + 3][c]) << 16);
    o.z = (unsigned)f2bf(tile[rb + 4][c]) | ((unsigned)f2bf(tile[rb + 5][c]) << 16);
    o.w = (unsigned)f2bf(tile[rb + 6][c]) | ((unsigned)f2bf(tile[rb + 7][c]) << 16);
    *(uint4*)&Wtb[(size_t)(c0 + c) * R + r0 + rb] = o;
  }
}

// ---------------- GEMM1: H = relu(Xg @ W1 + b1), bf16 out -------------------
// 128x128 tile, BK=64, xor-granule swizzle f(r)=r&7 (conflict-free, measured
// 0 conflicts in R3 gemm2), XCD-locality: blockIdx.x = expert. 32KB LDS.
__global__ __launch_bounds__(256) void moe_gemm1(const u16* __restrict__ Xg,
                                                 const u16* __restrict__ W1t,
                                                 const float* __restrict__ b1,
                                                 u16* __restrict__ H) {
  constexpr int K = D_MODEL;  // 1024
  const int e = blockIdx.x;
  const int n0 = blockIdx.y * 128;  // f
  const int m0 = blockIdx.z * 128;  // c
  const u16* A = Xg + ((size_t)e * CAPACITY + m0) * K;
  const u16* B = W1t + ((size_t)e * D_FF + n0) * K;
  __shared__ u16 As[128 * 64];  // 16 KB
  __shared__ u16 Bs[128 * 64];  // 16 KB
  const int tid = threadIdx.x, lane = tid & 63, wave = tid >> 6;
  const int wm = (wave >> 1) * 64, wn = (wave & 1) * 64;
  const int r_l = lane >> 3;                 // 0..7
  const int s8 = (lane & 7) ^ r_l;
  const u16* Ap[4]; const u16* Bp[4];
#pragma unroll
  for (int c = 0; c < 4; c++) {
    const int row = 32 * wave + 8 * c + r_l;
    Ap[c] = A + (size_t)row * K + s8 * 8;
    Bp[c] = B + (size_t)row * K + s8 * 8;
  }
  floatx4 acc[4][4] = {};
  const int lxor = lane & 7;
  for (int k0 = 0; k0 < K; k0 += 64) {
    __syncthreads();
#pragma unroll
    for (int c = 0; c < 4; c++)
      async_copy16(As + (32 * wave + 8 * c) * 64, Ap[c] + k0);
#pragma unroll
    for (int c = 0; c < 4; c++)
      async_copy16(Bs + (32 * wave + 8 * c) * 64, Bp[c] + k0);
    __syncthreads();
#pragma unroll
    for (int ks = 0; ks < 2; ks++) {
      const int s_log = ks * 4 + (lane >> 4);     // 0..7
      const int pgr = (s_log ^ lxor) * 8;
      short8 a[4], b[4];
#pragma unroll
      for (int i = 0; i < 4; i++)
        a[i] = *(const short8*)&As[(wm + i * 16 + (lane & 15)) * 64 + pgr];
#pragma unroll
      for (int j = 0; j < 4; j++)
        b[j] = *(const short8*)&Bs[(wn + j * 16 + (lane & 15)) * 64 + pgr];
#pragma unroll
      for (int i = 0; i < 4; i++)
#pragma unroll
        for (int j = 0; j < 4; j++)
          acc[i][j] = __builtin_amdgcn_mfma_f32_16x16x32_bf16(a[i], b[j], acc[i][j], 0, 0, 0);
    }
  }
  u16* Hb = H + (size_t)e * CAPACITY * D_FF;
#pragma unroll
  for (int j = 0; j < 4; j++) {
    const int n = n0 + wn + j * 16 + (lane & 15);
    const float bias = b1[e * D_FF + n];
#pragma unroll
    for (int i = 0; i < 4; i++) {
      const int rb = m0 + wm + i * 16 + ((lane >> 4) * 4);  // C/D: col=lane&15, row=quad*4+reg
#pragma unroll
      for (int r = 0; r < 4; r++) {
        float val = acc[i][j][r] + bias;
        val = val > 0.f ? val : 0.f;
        Hb[(size_t)(rb + r) * D_FF + n] = f2bf(val);
      }
    }
  }
}

// ---------------- GEMM2: out[tok] = (H @ W2 + b2) * gate, scatter -----------
// 128x128 tile, BK=128 (32 barriers instead of 64; 64KB LDS keeps the
// grid-limited 2 blocks/CU), 16-granule xor swizzle (same 2-way-free bank
// pattern as BK=64 which measured 0 conflicts), blockIdx.x = expert.
__global__ __launch_bounds__(256) void moe_gemm2(const u16* __restrict__ H,
                                                 const u16* __restrict__ W2t,
                                                 const float* __restrict__ b2,
                                                 const float* __restrict__ gates_sel,
                                                 const int* __restrict__ perm,
                                                 float* __restrict__ out) {
  constexpr int K = D_FF;  // 4096
  const int e = blockIdx.x;
  const int n0 = blockIdx.y * 128;  // d_out
  const int m0 = blockIdx.z * 128;  // c
  const u16* A = H + ((size_t)e * CAPACITY + m0) * K;
  const u16* B = W2t + ((size_t)e * D_MODEL + n0) * K;
  __shared__ u16 As[128 * 128];  // 32 KB
  __shared__ u16 Bs[128 * 128];  // 32 KB
  const int tid = threadIdx.x, lane = tid & 63, wave = tid >> 6;
  const int wm = (wave >> 1) * 64, wn = (wave & 1) * 64;
  // staging: call c (0..7) covers rows r0 = 32*wave + 4*c .. +3 (4 rows x 256B)
  // lane -> (row r0 + l/16, phys granule l&15) fetching logical granule
  // s = (l&15) ^ (row&15); rows repeat mod 16 every 4 calls -> 4 base ptrs.
  const int sub = lane >> 4;                 // 0..3
  const int p = lane & 15;                   // physical granule
  const u16* Apt[4]; const u16* Bpt[4];
#pragma unroll
  for (int c = 0; c < 4; c++) {
    const int row = 32 * wave + 4 * c + sub;
    const int s_log = p ^ (row & 15);
    Apt[c] = A + (size_t)row * K + s_log * 8;
    Bpt[c] = B + (size_t)row * K + s_log * 8;
  }
  floatx4 acc[4][4] = {};
  for (int k0 = 0; k0 < K; k0 += 128) {
    __syncthreads();
#pragma unroll
    for (int c = 0; c < 8; c++)
      async_copy16(As + (32 * wave + 4 * c) * 128, Apt[c & 3] + (c >> 2) * (16 * K) + k0);
#pragma unroll
    for (int c = 0; c < 8; c++)
      async_copy16(Bs + (32 * wave + 4 * c) * 128, Bpt[c & 3] + (c >> 2) * (16 * K) + k0);
    __syncthreads();
#pragma unroll
    for (int ks = 0; ks < 4; ks++) {
      const int g_log = ks * 4 + (lane >> 4);      // 0..15
      const int pgr = (g_log ^ (lane & 15)) * 8;   // physical granule (elems)
      short8 a[4], b[4];
#pragma unroll
      for (int i = 0; i < 4; i++)
        a[i] = *(const short8*)&As[(wm + i * 16 + (lane & 15)) * 128 + pgr];
#pragma unroll
      for (int j = 0; j < 4; j++)
        b[j] = *(const short8*)&Bs[(wn + j * 16 + (lane & 15)) * 128 + pgr];
#pragma unroll
      for (int i = 0; i < 4; i++)
#pragma unroll
        for (int j = 0; j < 4; j++)
          acc[i][j] = __builtin_amdgcn_mfma_f32_16x16x32_bf16(a[i], b[j], acc[i][j], 0, 0, 0);
    }
  }
  float bias[4];
#pragma unroll
  for (int j = 0; j < 4; j++) bias[j] = b2[e * D_MODEL + n0 + wn + j * 16 + (lane & 15)];
#pragma unroll
  for (int i = 0; i < 4; i++) {
#pragma unroll
    for (int r = 0; r < 4; r++) {
      const int c = m0 + wm + i * 16 + (lane >> 4) * 4 + r;
      const int t = perm[e * CAPACITY + c];
      if (t < 0) continue;  // dropped / empty slot
      const float gv = gates_sel[e * CAPACITY + c];
      float* orow = out + (size_t)t * D_MODEL + n0 + wn;
#pragma unroll
      for (int j = 0; j < 4; j++)
        orow[j * 16 + (lane & 15)] = (acc[i][j][r] + bias[j]) * gv;
    }
  }
}

// ---------------- launch -----------------------------------------------------
extern "C" void kernel_launch(void* const* d_in, const int* in_sizes, int n_in,
                              void* d_out, int out_size, void* d_ws, size_t ws_size,
                              hipStream_t stream) {
  const float* x  = (const float*)d_in[0];  // [4,2048,1024]
  const float* Wr = (const float*)d_in[1];  // [1024,8]
  const float* W1 = (const float*)d_in[2];  // [8,1024,4096]
  const float* b1 = (const float*)d_in[3];  // [8,4096]
  const float* W2 = (const float*)d_in[4];  // [8,4096,1024]
  const float* b2 = (const float*)d_in[5];  // [8,1024]
  float* out = (float*)d_out;               // 8388608 + 1 (loss)

  char* ws = (char*)d_ws;
  u16* W1t = (u16*)ws;            ws += (size_t)8 * 4096 * 1024 * 2;  // [E][F][D] bf16
  u16* W2t = (u16*)ws;            ws += (size_t)8 * 1024 * 4096 * 2;  // [E][D][F] bf16
  u16* Xg  = (u16*)ws;            ws += (size_t)8 * 1024 * 1024 * 2;  // [E][C][D] bf16
  u16* H   = (u16*)ws;            ws += (size_t)8 * 1024 * 4096 * 2;  // [E][C][F] bf16
  float* gate_arr  = (float*)ws;  ws += (size_t)T_TOKENS * 4;
  int*   exp_arr   = (int*)ws;    ws += (size_t)T_TOKENS * 4;
  float* partial   = (float*)ws;  ws += (size_t)2048 * 8 * 4;
  int*   list_tok  = (int*)ws;    ws += (size_t)8 * T_TOKENS * 4;
  float* list_gate = (float*)ws;  ws += (size_t)8 * T_TOKENS * 4;
  int*   perm      = (int*)ws;    ws += (size_t)8 * 1024 * 4;
  float* gates_sel = (float*)ws;  ws += (size_t)8 * 1024 * 4;
  int*   counts    = (int*)ws;    ws += 8 * 4;

  hipMemsetAsync(d_out, 0, (size_t)out_size * sizeof(float), stream);
  hipMemsetAsync(perm, 0xFF, 8 * 1024 * 4, stream);      // -1 = empty slot
  hipMemsetAsync(gates_sel, 0, 8 * 1024 * 4, stream);

  transpose64<<<dim3(64, 16, 8), 256, 0, stream>>>(W1, W1t, 1024, 4096);
  transpose64<<<dim3(16, 64, 8), 256, 0, stream>>>(W2, W2t, 4096, 1024);
  moe_logits<<<2048, 256, 0, stream>>>(x, Wr, gate_arr, exp_arr, partial);
  moe_build<<<8, 256, 0, stream>>>(gate_arr, exp_arr, counts, list_tok, list_gate);
  moe_rank3<<<64, 256, 0, stream>>>(counts, list_tok, list_gate, perm, gates_sel);
  moe_loss2<<<1, 256, 0, stream>>>(counts, partial, out + (size_t)8388608);
  moe_gather<<<8192, 256, 0, stream>>>(x, perm, Xg);
  moe_gemm1<<<dim3(8, 32, 8), 256, 0, stream>>>(Xg, W1t, b1, H);
  moe_gemm2<<<dim3(8, 8, 8), 256, 0, stream>>>(H, W2t, b2, gates_sel, perm, out);
}